// Round 1
// baseline (342.223 us; speedup 1.0000x reference)
//
#include <hip/hip_runtime.h>

typedef __bf16 bf16_t;
typedef __attribute__((ext_vector_type(8))) __bf16 bf16x8;
typedef __attribute__((ext_vector_type(4))) float floatx4;

#define MFMA16(a, b, c) __builtin_amdgcn_mfma_f32_16x16x32_bf16((a), (b), (c), 0, 0, 0)

constexpr int TT = 128;   // sequence length
constexpr int CD = 384;   // n_emb
constexpr int HS = 64;    // head size
constexpr int W_ELEMS = HS * CD;  // 24576 per projection

// LDS layout (units: bf16 elements)
constexpr int QK_STR = 72;    // q/k rows [t][h], 64+8 pad -> 2-way bank alias (free), 16B-aligned rows
constexpr int VT_STR = 136;   // v^T rows [h][t] and P rows [t][s], 128+8 pad
constexpr int QS_OFF = 0;
constexpr int KS_OFF = TT * QK_STR;        // 9216
constexpr int VT_OFF = 2 * TT * QK_STR;    // 18432
constexpr int PS_OFF = 0;                  // P overlays q+k after they are dead (17408 <= 18432)
constexpr int SMEM_N = 2 * TT * QK_STR + HS * VT_STR;  // 27136 bf16 = 54272 B -> 2 blocks/CU

// ---- pre-kernel: Wq,Wk,Wv fp32 -> bf16 into ws as [3][64][384] (order q,k,v) ----
__global__ void wconv_kernel(const float* __restrict__ wq, const float* __restrict__ wk,
                             const float* __restrict__ wv, bf16_t* __restrict__ out) {
    int i = blockIdx.x * 256 + threadIdx.x;
    if (i < W_ELEMS)            out[i] = (bf16_t)wq[i];
    else if (i < 2 * W_ELEMS)   out[i] = (bf16_t)wk[i - W_ELEMS];
    else if (i < 3 * W_ELEMS)   out[i] = (bf16_t)wv[i - 2 * W_ELEMS];
}

// ---- fused attention head: one block per batch element, 4 waves, wave w owns rows [32w,32w+32) ----
__launch_bounds__(256, 2)
__global__ void attn_kernel(const float* __restrict__ x, const bf16_t* __restrict__ wc,
                            float* __restrict__ out) {
    __shared__ bf16_t smem[SMEM_N];
    const int b    = blockIdx.x;
    const int lane = threadIdx.x & 63;
    const int w    = threadIdx.x >> 6;  // wave id 0..3
    const int l15  = lane & 15;
    const int g    = lane >> 4;         // 16-lane group 0..3
    const float* xb = x + (size_t)b * TT * CD;

    // ================= Phase 1: q,k,v projections =================
    floatx4 accq[2][4], acck[2][4], accv[2][4];
#pragma unroll
    for (int mt = 0; mt < 2; ++mt)
#pragma unroll
        for (int nt = 0; nt < 4; ++nt) {
            accq[mt][nt] = (floatx4)0.0f;
            acck[mt][nt] = (floatx4)0.0f;
            accv[mt][nt] = (floatx4)0.0f;
        }

    for (int kk = 0; kk < CD; kk += 32) {
        const int c = kk + 8 * g;  // k-offset for this lane's A/B fragment slots
        bf16x8 a[2];
#pragma unroll
        for (int mt = 0; mt < 2; ++mt) {
            const int row = 32 * w + 16 * mt + l15;
            const float* p = xb + row * CD + c;
            float4 f0 = *(const float4*)p;
            float4 f1 = *(const float4*)(p + 4);
            bf16x8 t;
            t[0] = (bf16_t)f0.x; t[1] = (bf16_t)f0.y; t[2] = (bf16_t)f0.z; t[3] = (bf16_t)f0.w;
            t[4] = (bf16_t)f1.x; t[5] = (bf16_t)f1.y; t[6] = (bf16_t)f1.z; t[7] = (bf16_t)f1.w;
            a[mt] = t;
        }
#pragma unroll
        for (int nt = 0; nt < 4; ++nt) {
            const int h = 16 * nt + l15;
            bf16x8 bq = *(const bf16x8*)(wc + 0 * W_ELEMS + h * CD + c);
            bf16x8 bk = *(const bf16x8*)(wc + 1 * W_ELEMS + h * CD + c);
            bf16x8 bv = *(const bf16x8*)(wc + 2 * W_ELEMS + h * CD + c);
            accq[0][nt] = MFMA16(a[0], bq, accq[0][nt]);
            accq[1][nt] = MFMA16(a[1], bq, accq[1][nt]);
            acck[0][nt] = MFMA16(a[0], bk, acck[0][nt]);
            acck[1][nt] = MFMA16(a[1], bk, acck[1][nt]);
            accv[0][nt] = MFMA16(a[0], bv, accv[0][nt]);
            accv[1][nt] = MFMA16(a[1], bv, accv[1][nt]);
        }
    }

    // Write q,k as [t][h]; v transposed as [h][t]. C/D layout: col=lane&15, row=4*g+reg.
#pragma unroll
    for (int mt = 0; mt < 2; ++mt)
#pragma unroll
        for (int nt = 0; nt < 4; ++nt) {
            const int t0 = 32 * w + 16 * mt + 4 * g;
            const int h  = 16 * nt + l15;
#pragma unroll
            for (int r = 0; r < 4; ++r) {
                smem[QS_OFF + (t0 + r) * QK_STR + h] = (bf16_t)accq[mt][nt][r];
                smem[KS_OFF + (t0 + r) * QK_STR + h] = (bf16_t)acck[mt][nt][r];
                smem[VT_OFF + h * VT_STR + t0 + r]   = (bf16_t)accv[mt][nt][r];
            }
        }
    __syncthreads();  // sync #1: qkv visible to all waves

    // ================= Phase 2: S = q k^T (skip fully-masked causal tiles) =================
    floatx4 sacc[2][8];
#pragma unroll
    for (int mt = 0; mt < 2; ++mt)
#pragma unroll
        for (int nt = 0; nt < 8; ++nt) sacc[mt][nt] = (floatx4)0.0f;

#pragma unroll
    for (int kt = 0; kt < 2; ++kt) {  // K = 64 -> 2 steps
        const int hh = 32 * kt + 8 * g;
        bf16x8 aq[2];
        aq[0] = *(const bf16x8*)(smem + QS_OFF + (32 * w + l15) * QK_STR + hh);
        aq[1] = *(const bf16x8*)(smem + QS_OFF + (32 * w + 16 + l15) * QK_STR + hh);
#pragma unroll
        for (int nt = 0; nt < 8; ++nt) {
            if (16 * nt <= 32 * w + 31) {  // wave-uniform: tile touches s <= t somewhere
                bf16x8 bk = *(const bf16x8*)(smem + KS_OFF + (16 * nt + l15) * QK_STR + hh);
                if (16 * nt <= 32 * w + 15) sacc[0][nt] = MFMA16(aq[0], bk, sacc[0][nt]);
                sacc[1][nt] = MFMA16(aq[1], bk, sacc[1][nt]);
            }
        }
    }
    __syncthreads();  // sync #2: everyone done reading q/k before P overlays them

    // ================= causal mask + softmax, P -> LDS bf16 =================
    const float scale = 0.05103103630798287f;  // 384^-0.5
#pragma unroll
    for (int mt = 0; mt < 2; ++mt) {
#pragma unroll
        for (int r = 0; r < 4; ++r) {
            const int t = 32 * w + 16 * mt + 4 * g + r;
            float vals[8];
            float vmax = -__builtin_inff();
#pragma unroll
            for (int nt = 0; nt < 8; ++nt) {
                const int s = 16 * nt + l15;
                float v = (s <= t) ? sacc[mt][nt][r] * scale : -__builtin_inff();
                vals[nt] = v;
                vmax = fmaxf(vmax, v);
            }
            vmax = fmaxf(vmax, __shfl_xor(vmax, 1));
            vmax = fmaxf(vmax, __shfl_xor(vmax, 2));
            vmax = fmaxf(vmax, __shfl_xor(vmax, 4));
            vmax = fmaxf(vmax, __shfl_xor(vmax, 8));
            float sum = 0.0f;
#pragma unroll
            for (int nt = 0; nt < 8; ++nt) {
                float e = __expf(vals[nt] - vmax);
                vals[nt] = e;
                sum += e;
            }
            sum += __shfl_xor(sum, 1);
            sum += __shfl_xor(sum, 2);
            sum += __shfl_xor(sum, 4);
            sum += __shfl_xor(sum, 8);
            const float inv = 1.0f / sum;
#pragma unroll
            for (int nt = 0; nt < 8; ++nt)
                smem[PS_OFF + t * VT_STR + 16 * nt + l15] = (bf16_t)(vals[nt] * inv);
        }
    }
    // no sync needed: each wave only reads back its own P rows

    // ================= O = P v (skip all-zero k-chunks past the causal edge) =================
    floatx4 oacc[2][4];
#pragma unroll
    for (int mt = 0; mt < 2; ++mt)
#pragma unroll
        for (int nt = 0; nt < 4; ++nt) oacc[mt][nt] = (floatx4)0.0f;

    for (int st = 0; st <= w; ++st) {  // s-chunks of 32; wave w needs s < 32(w+1)
        const int ss = 32 * st + 8 * g;
        bf16x8 ap[2];
        ap[0] = *(const bf16x8*)(smem + PS_OFF + (32 * w + l15) * VT_STR + ss);
        ap[1] = *(const bf16x8*)(smem + PS_OFF + (32 * w + 16 + l15) * VT_STR + ss);
#pragma unroll
        for (int nt = 0; nt < 4; ++nt) {
            bf16x8 bv = *(const bf16x8*)(smem + VT_OFF + (16 * nt + l15) * VT_STR + ss);
            oacc[0][nt] = MFMA16(ap[0], bv, oacc[0][nt]);
            oacc[1][nt] = MFMA16(ap[1], bv, oacc[1][nt]);
        }
    }

    float* ob = out + (size_t)b * TT * HS;
#pragma unroll
    for (int mt = 0; mt < 2; ++mt)
#pragma unroll
        for (int nt = 0; nt < 4; ++nt) {
            const int t0 = 32 * w + 16 * mt + 4 * g;
            const int h  = 16 * nt + l15;
#pragma unroll
            for (int r = 0; r < 4; ++r)
                ob[(t0 + r) * HS + h] = oacc[mt][nt][r];
        }
}

extern "C" void kernel_launch(void* const* d_in, const int* in_sizes, int n_in,
                              void* d_out, int out_size, void* d_ws, size_t ws_size,
                              hipStream_t stream) {
    // setup_inputs order: x, Wk, Wq, Wv
    const float* x  = (const float*)d_in[0];
    const float* wk = (const float*)d_in[1];
    const float* wq = (const float*)d_in[2];
    const float* wv = (const float*)d_in[3];
    bf16_t* wc = (bf16_t*)d_ws;   // [3][64][384] bf16, order q,k,v
    float* out = (float*)d_out;

    wconv_kernel<<<(3 * W_ELEMS + 255) / 256, 256, 0, stream>>>(wq, wk, wv, wc);
    attn_kernel<<<1024, 256, 0, stream>>>(x, wc, out);
}